// Round 8
// baseline (490.021 us; speedup 1.0000x reference)
//
#include <hip/hip_runtime.h>
#include <stdint.h>

using fx4   = __attribute__((ext_vector_type(4))) float;
using half8 = __attribute__((ext_vector_type(8))) _Float16;

__device__ __forceinline__ ushort f2h(float x) {
  _Float16 h = (_Float16)x;
  union { _Float16 hv; ushort u; } v; v.hv = h;
  return v.u;
}

__device__ __forceinline__ void gload_lds16(const ushort* g, ushort* l) {
  __builtin_amdgcn_global_load_lds(
      (__attribute__((address_space(1))) const void*)g,
      (__attribute__((address_space(3))) void*)l, 16, 0, 0);
}

#define MFMA16(a, b, c) __builtin_amdgcn_mfma_f32_16x16x32_f16(a, b, c, 0, 0, 0)

// Shared GEMM body. C[m][n] = sum_k A[m][k]*B[n][k] (B transposed, fp16, fp32 acc)
// flags: 1=relu, 2=store fp16, 16=transposed fp16 store (C[col*ldc+row])
__device__ __forceinline__ void gemm_body(
    const ushort* __restrict__ A, int lda,
    const ushort* __restrict__ B, int ldb,
    const float* __restrict__ bias,
    void* __restrict__ C, int ldc,
    int K, int flags, int bx, int by,
    ushort* As, ushort* Bs)
{
  const int tid  = threadIdx.x;
  const int lane = tid & 63;
  const int wave = tid >> 6;
  const int wm   = (wave >> 1) * 64;
  const int wn   = (wave & 1) * 64;
  const long long bm = (long long)by * 128;
  const long long bn = (long long)bx * 128;

  const int srow = tid >> 2;
  const int skq  = (tid & 3) * 8;
  const ushort* a0 = A + (bm + srow) * lda + skq;
  const ushort* a1 = a0 + 64LL * lda;
  const ushort* b0 = B + (bn + srow) * ldb + skq;
  const ushort* b1 = b0 + 64LL * ldb;
  ushort* lA0 = &As[tid * 8];
  ushort* lA1 = &As[2048 + tid * 8];
  ushort* lB0 = &Bs[tid * 8];
  ushort* lB1 = &Bs[2048 + tid * 8];

  fx4 acc[4][4] = {};
  const ushort* ap = &As[(wm + (lane & 15)) * 32 + (lane >> 4) * 8];
  const ushort* bp = &Bs[(wn + (lane & 15)) * 32 + (lane >> 4) * 8];

  for (int k0 = 0; k0 < K; k0 += 32) {
    gload_lds16(a0, lA0);
    gload_lds16(a1, lA1);
    gload_lds16(b0, lB0);
    gload_lds16(b1, lB1);
    a0 += 32; a1 += 32; b0 += 32; b1 += 32;
    __syncthreads();
    half8 af[4], bv[4];
#pragma unroll
    for (int t = 0; t < 4; ++t) {
      af[t] = *(const half8*)(ap + t * 16 * 32);
      bv[t] = *(const half8*)(bp + t * 16 * 32);
    }
#pragma unroll
    for (int i = 0; i < 4; ++i)
#pragma unroll
      for (int j = 0; j < 4; ++j)
        acc[i][j] = MFMA16(af[i], bv[j], acc[i][j]);
    __syncthreads();
  }

  const int col0 = (int)bn + wn + (lane & 15);
  const int row0 = (int)bm + wm + ((lane >> 4) << 2);

  if (flags & 16) {
    ushort* Ch = (ushort*)C;
#pragma unroll
    for (int j = 0; j < 4; ++j) {
      const int col = col0 + j * 16;
      const float bvv = bias ? bias[col] : 0.0f;
#pragma unroll
      for (int i = 0; i < 4; ++i) {
        const int row = row0 + i * 16;
        ushort4 o;
        o.x = f2h(acc[i][j][0] + bvv);
        o.y = f2h(acc[i][j][1] + bvv);
        o.z = f2h(acc[i][j][2] + bvv);
        o.w = f2h(acc[i][j][3] + bvv);
        *(ushort4*)(Ch + (long long)col * ldc + row) = o;
      }
    }
    return;
  }

  float*  Cf = (float*)C;
  ushort* Ch = (ushort*)C;
#pragma unroll
  for (int j = 0; j < 4; ++j) {
    const int col = col0 + j * 16;
    const float bvv = bias ? bias[col] : 0.0f;
#pragma unroll
    for (int i = 0; i < 4; ++i) {
      const long long row = row0 + i * 16;
#pragma unroll
      for (int r = 0; r < 4; ++r) {
        float v = acc[i][j][r] + bvv;
        if (flags & 1) v = fmaxf(v, 0.0f);
        if (flags & 2) Ch[(row + r) * ldc + col] = f2h(v);
        else           Cf[(row + r) * ldc + col] = v;
      }
    }
  }
}

__global__ __launch_bounds__(256)
void gemm_bt(const ushort* __restrict__ A, int lda, long long sA,
             const ushort* __restrict__ B, int ldb, long long sB,
             const float* __restrict__ bias,
             void* __restrict__ C, int ldc, long long sC,
             int K, int flags)
{
  __shared__ ushort As[128 * 32];
  __shared__ ushort Bs[128 * 32];
  const int z = blockIdx.z;
  void* Cz = (flags & (2 | 16)) ? (void*)((ushort*)C + (long long)z * sC)
                                : (void*)((float*)C + (long long)z * sC);
  gemm_body(A + (long long)z * sA, lda, B + (long long)z * sB, ldb, bias,
            Cz, ldc, K, flags, blockIdx.x, blockIdx.y, As, Bs);
}

// z=0: EMBT = (H[:,:1024] @ We2 + be2)^T ; z=1: KQ = H[:,1024:] @ Wk2 + bk2
__global__ __launch_bounds__(256)
void gemm2_pair(const ushort* __restrict__ H, const ushort* __restrict__ W2c,
                const float* __restrict__ be2, const float* __restrict__ bk2,
                ushort* __restrict__ EMBT, ushort* __restrict__ KQ)
{
  __shared__ ushort As[128 * 32];
  __shared__ ushort Bs[128 * 32];
  if (blockIdx.z == 0)
    gemm_body(H, 2048, W2c, 1024, be2, EMBT, 16384, 1024, 16,
              blockIdx.x, blockIdx.y, As, Bs);
  else
    gemm_body(H + 1024, 2048, W2c + 524288, 1024, bk2, KQ, 512, 1024, 2,
              blockIdx.x, blockIdx.y, As, Bs);
}

// Flash attention, m97-style 2-barrier K-loop. Block = (batch, 32-row Q-tile),
// 256 thr / 4 waves: wave = (qg = w&1 -> 16 q rows, dh = w>>1 -> 256 d cols).
// Token-tile 32: K (16KB) + V (32KB) staged to LDS via global_load_lds, shared
// by all waves. Each wave sees ALL tokens for its q rows -> online softmax is
// fully wave-local (no cross-wave merges, no mid-tile barriers; P is
// wave-private LDS, write->read guarded by lgkmcnt only). QK duplicated x2
// across dh (MFMA-cheap, avoids a barrier). 2 barriers/tile; grid 512 blocks
// -> 2 blocks/CU so barrier drains overlap across blocks (m114 mechanism).
__global__ __launch_bounds__(256, 2)
void attn_fused(const ushort* __restrict__ KQ, const ushort* __restrict__ EMBT,
                float* __restrict__ out)
{
  __shared__ ushort Ks[8 * 32 * 32];   // [dc 8][tok 32][32]   16 KB
  __shared__ ushort Vs[512 * 32];      // [d 512][tok 32]      32 KB
  __shared__ ushort Ps[4 * 16 * 40];   // per-wave [q 16][40]   5 KB

  const int tid  = threadIdx.x;
  const int lane = tid & 63;
  const int w    = tid >> 6;
  const int c    = lane & 15;
  const int quad = lane >> 4;
  const int qg   = w & 1;
  const int dh   = (w >> 1) * 256;
  const int z    = blockIdx.x;          // batch -> XCD locality
  const long long tb = (long long)z * 2048;
  const int q0   = blockIdx.y * 32;

  ushort* Pw = Ps + w * 640;
  // wave's Q A-frag base (global; 8 KB/wave, L1-resident after tile 0)
  const ushort* Qg = KQ + (tb + q0 + qg * 16 + c) * 512 + 256 + quad * 8;

  float m_r[4], l_r[4];
#pragma unroll
  for (int r = 0; r < 4; ++r) { m_r[r] = -3.0e38f; l_r[r] = 0.0f; }
  fx4 o[16] = {};

  for (int t0 = 0; t0 < 2048; t0 += 32) {
    // ---- stage K-tile + V-tile (async DMA, no VGPR round-trip) ----
#pragma unroll
    for (int i = 0; i < 4; ++i) {
      const int u = i * 256 + tid;             // 0..1023
      const int dc = u >> 7, tok = (u >> 2) & 31, c8 = (u & 3) * 8;
      gload_lds16(KQ + (tb + t0 + tok) * 512 + dc * 32 + c8, Ks + u * 8);
    }
#pragma unroll
    for (int i = 0; i < 8; ++i) {
      const int u = i * 256 + tid;             // 0..2047
      const int d = u >> 2, c8 = (u & 3) * 8;
      gload_lds16(EMBT + (long long)d * 16384 + tb + t0 + c8, Vs + u * 8);
    }
    __syncthreads();

    // ---- QK: S[16 q][32 tok] for this wave's qg ----
    fx4 s[2] = {};
#pragma unroll
    for (int dc = 0; dc < 8; ++dc) {
      const half8 a  = *(const half8*)(Qg + dc * 32);
      const half8 b0 = *(const half8*)(Ks + dc * 1024 + c * 32 + quad * 8);
      const half8 b1 = *(const half8*)(Ks + dc * 1024 + (16 + c) * 32 + quad * 8);
      s[0] = MFMA16(a, b0, s[0]);
      s[1] = MFMA16(a, b1, s[1]);
    }

    // ---- wave-local online softmax (rows = quad*4+r) ----
    fx4 rm;
#pragma unroll
    for (int r = 0; r < 4; ++r) rm[r] = fmaxf(s[0][r], s[1][r]);
#pragma unroll
    for (int off = 1; off < 16; off <<= 1)
#pragma unroll
      for (int r = 0; r < 4; ++r) rm[r] = fmaxf(rm[r], __shfl_xor(rm[r], off, 64));
    float alpha[4];
#pragma unroll
    for (int r = 0; r < 4; ++r) {
      const float mn = fmaxf(m_r[r], rm[r]);
      alpha[r] = __expf(m_r[r] - mn);
      m_r[r] = mn;
      const float e0 = __expf(s[0][r] - mn);
      const float e1 = __expf(s[1][r] - mn);
      l_r[r] = alpha[r] * l_r[r] + e0 + e1;    // per-lane partial (c-slice)
      Pw[(quad * 4 + r) * 40 + c]      = f2h(e0);
      Pw[(quad * 4 + r) * 40 + 16 + c] = f2h(e1);
    }
#pragma unroll
    for (int n = 0; n < 16; ++n)
#pragma unroll
      for (int r = 0; r < 4; ++r) o[n][r] *= alpha[r];

    // ---- PV: pa from wave-private Ps (lgkmcnt only), vb from shared Vs ----
    const half8 pa = *(const half8*)(Pw + c * 40 + quad * 8);
#pragma unroll
    for (int n = 0; n < 16; ++n) {
      const half8 vb = *(const half8*)(Vs + (dh + n * 16 + c) * 32 + quad * 8);
      o[n] = MFMA16(pa, vb, o[n]);
    }
    __syncthreads();   // all waves done with Ks/Vs before next stage
  }

  // ---- epilogue: reduce l over the 16-lane token groups, normalize, store ----
#pragma unroll
  for (int off = 1; off < 16; off <<= 1)
#pragma unroll
    for (int r = 0; r < 4; ++r) l_r[r] += __shfl_xor(l_r[r], off, 64);
  float linv[4];
#pragma unroll
  for (int r = 0; r < 4; ++r) linv[r] = 1.0f / l_r[r];

  float* ob = out + (tb + q0 + qg * 16) * 512 + dh;
#pragma unroll
  for (int n = 0; n < 16; ++n)
#pragma unroll
    for (int r = 0; r < 4; ++r)
      ob[(long long)(quad * 4 + r) * 512 + n * 16 + c] = o[n][r] * linv[r];
}

// fp32 [R][C] -> fp16 [C][R], two inputs selected by blockIdx.z
__global__ __launch_bounds__(256)
void transpose_cast_w2(const float* __restrict__ in0, const float* __restrict__ in1,
                       ushort* __restrict__ out0, ushort* __restrict__ out1,
                       int R, int C) {
  __shared__ float tile[32][33];
  const float* in  = blockIdx.z ? in1 : in0;
  ushort*      outp = blockIdx.z ? out1 : out0;
  const int c0 = blockIdx.x * 32, r0 = blockIdx.y * 32;
  const int tx = threadIdx.x & 31, ty = threadIdx.x >> 5;
#pragma unroll
  for (int i = 0; i < 32; i += 8)
    tile[ty + i][tx] = in[(long long)(r0 + ty + i) * C + (c0 + tx)];
  __syncthreads();
#pragma unroll
  for (int i = 0; i < 32; i += 8)
    outp[(long long)(c0 + ty + i) * R + (r0 + tx)] = f2h(tile[tx][ty + i]);
}

__global__ __launch_bounds__(256)
void cast_f32_f16(const float* __restrict__ in, ushort* __restrict__ out) {
  const long long i = ((long long)blockIdx.x * 256 + threadIdx.x) * 4;
  const float4 v = *(const float4*)(in + i);
  ushort4 o;
  o.x = f2h(v.x); o.y = f2h(v.y); o.z = f2h(v.z); o.w = f2h(v.w);
  *(ushort4*)(out + i) = o;
}

__global__ __launch_bounds__(256)
void concat_bias(const float* __restrict__ b0, const float* __restrict__ b1,
                 float* __restrict__ out) {
  const int i = blockIdx.x * 256 + threadIdx.x;
  out[i] = (i < 1024) ? b0[i] : b1[i - 1024];
}

extern "C" void kernel_launch(void* const* d_in, const int* in_sizes, int n_in,
                              void* d_out, int out_size, void* d_ws, size_t ws_size,
                              hipStream_t stream) {
  (void)in_sizes; (void)n_in; (void)out_size; (void)ws_size;
  const float* x   = (const float*)d_in[0];
  const float* We1 = (const float*)d_in[1];
  const float* be1 = (const float*)d_in[2];
  const float* We2 = (const float*)d_in[3];
  const float* be2 = (const float*)d_in[4];
  const float* Wk1 = (const float*)d_in[5];
  const float* bk1 = (const float*)d_in[6];
  const float* Wk2 = (const float*)d_in[7];
  const float* bk2 = (const float*)d_in[8];
  float* out = (float*)d_out;
  char* ws = (char*)d_ws;

  ushort* Xb   = (ushort*)(ws + 0);            // 16.78 MB, dead after gemm1
  ushort* W2c  = (ushort*)(ws + 0);            // 2 MB, written after gemm1
  ushort* H    = (ushort*)(ws + 16777216);     // 16384x2048 fp16 = 67.1 MB
  ushort* EMBT = (ushort*)(ws + 83886080);     // [512][16384] fp16 = 16.78 MB
  ushort* KQ   = (ushort*)(ws + 100663296);    // 16384x512 fp16 = 16.78 MB
  float*  b1c  = (float*)(ws + 117440512);     // 2048 fp32
  ushort* W1c  = (ushort*)(ws + 117448704);    // 2 MB

  cast_f32_f16<<<dim3(8192), 256, 0, stream>>>(x, Xb);
  transpose_cast_w2<<<dim3(32, 16, 2), 256, 0, stream>>>(We1, Wk1, W1c, W1c + 524288, 512, 1024);
  concat_bias<<<dim3(8), 256, 0, stream>>>(be1, bk1, b1c);

  // H = relu(x @ [We1|Wk1] + [be1|bk1])   [16384,2048]
  gemm_bt<<<dim3(16, 128, 1), 256, 0, stream>>>(Xb, 512, 0, W1c, 512, 0, b1c,
                                                H, 2048, 0, 512, 1 | 2);

  transpose_cast_w2<<<dim3(16, 32, 2), 256, 0, stream>>>(We2, Wk2, W2c, W2c + 524288, 1024, 512);

  // z=0: EMBT = (H[:,:1024]@We2+be2)^T ; z=1: KQ = H[:,1024:]@Wk2+bk2
  gemm2_pair<<<dim3(4, 128, 2), 256, 0, stream>>>(H, W2c, be2, bk2, EMBT, KQ);

  // flash attention: grid x=batch (XCD-local), y=32-row Q-tile -> 512 blocks
  attn_fused<<<dim3(8, 64), 256, 0, stream>>>(KQ, EMBT, out);
}

// Round 9
// 410.407 us; speedup vs baseline: 1.1940x; 1.1940x over previous
//
#include <hip/hip_runtime.h>
#include <stdint.h>

using fx4   = __attribute__((ext_vector_type(4))) float;
using half8 = __attribute__((ext_vector_type(8))) _Float16;

__device__ __forceinline__ ushort f2h(float x) {
  _Float16 h = (_Float16)x;
  union { _Float16 hv; ushort u; } v; v.hv = h;
  return v.u;
}

__device__ __forceinline__ void gload_lds16(const ushort* g, ushort* l) {
  __builtin_amdgcn_global_load_lds(
      (__attribute__((address_space(1))) const void*)g,
      (__attribute__((address_space(3))) void*)l, 16, 0, 0);
}

#define MFMA16(a, b, c) __builtin_amdgcn_mfma_f32_16x16x32_f16(a, b, c, 0, 0, 0)

// Shared GEMM body. C[m][n] = sum_k A[m][k]*B[n][k] (B transposed, fp16, fp32 acc)
// flags: 1=relu, 2=store fp16 row-major,
//        16 = V-panel store: C[(row>>5)*16384 + col*32 + (row&31)]  (VT layout)
//        32 = KQ split store: col<256 -> KT panels, col>=256 -> Qm row-major (C2)
__device__ __forceinline__ void gemm_body(
    const ushort* __restrict__ A, int lda,
    const ushort* __restrict__ B, int ldb,
    const float* __restrict__ bias,
    void* __restrict__ C, int ldc,
    int K, int flags, int bx, int by,
    ushort* As, ushort* Bs, ushort* __restrict__ C2 = nullptr)
{
  const int tid  = threadIdx.x;
  const int lane = tid & 63;
  const int wave = tid >> 6;
  const int wm   = (wave >> 1) * 64;
  const int wn   = (wave & 1) * 64;
  const long long bm = (long long)by * 128;
  const long long bn = (long long)bx * 128;

  const int srow = tid >> 2;
  const int skq  = (tid & 3) * 8;
  const ushort* a0 = A + (bm + srow) * lda + skq;
  const ushort* a1 = a0 + 64LL * lda;
  const ushort* b0 = B + (bn + srow) * ldb + skq;
  const ushort* b1 = b0 + 64LL * ldb;
  ushort* lA0 = &As[tid * 8];
  ushort* lA1 = &As[2048 + tid * 8];
  ushort* lB0 = &Bs[tid * 8];
  ushort* lB1 = &Bs[2048 + tid * 8];

  fx4 acc[4][4] = {};
  const ushort* ap = &As[(wm + (lane & 15)) * 32 + (lane >> 4) * 8];
  const ushort* bp = &Bs[(wn + (lane & 15)) * 32 + (lane >> 4) * 8];

  for (int k0 = 0; k0 < K; k0 += 32) {
    gload_lds16(a0, lA0);
    gload_lds16(a1, lA1);
    gload_lds16(b0, lB0);
    gload_lds16(b1, lB1);
    a0 += 32; a1 += 32; b0 += 32; b1 += 32;
    __syncthreads();
    half8 af[4], bv[4];
#pragma unroll
    for (int t = 0; t < 4; ++t) {
      af[t] = *(const half8*)(ap + t * 16 * 32);
      bv[t] = *(const half8*)(bp + t * 16 * 32);
    }
#pragma unroll
    for (int i = 0; i < 4; ++i)
#pragma unroll
      for (int j = 0; j < 4; ++j)
        acc[i][j] = MFMA16(af[i], bv[j], acc[i][j]);
    __syncthreads();
  }

  const int col0 = (int)bn + wn + (lane & 15);
  const int row0 = (int)bm + wm + ((lane >> 4) << 2);

  if (flags & 16) {        // VT panel store
    ushort* Ch = (ushort*)C;
#pragma unroll
    for (int j = 0; j < 4; ++j) {
      const int col = col0 + j * 16;
      const float bvv = bias ? bias[col] : 0.0f;
#pragma unroll
      for (int i = 0; i < 4; ++i) {
        const int row = row0 + i * 16;
        ushort4 o;
        o.x = f2h(acc[i][j][0] + bvv);
        o.y = f2h(acc[i][j][1] + bvv);
        o.z = f2h(acc[i][j][2] + bvv);
        o.w = f2h(acc[i][j][3] + bvv);
        *(ushort4*)(Ch + (long long)(row >> 5) * 16384 + (long long)col * 32 + (row & 31)) = o;
      }
    }
    return;
  }

  if (flags & 32) {        // KT panels + Qm split
    ushort* KTp = (ushort*)C;
#pragma unroll
    for (int j = 0; j < 4; ++j) {
      const int col = col0 + j * 16;
      const float bvv = bias ? bias[col] : 0.0f;
#pragma unroll
      for (int i = 0; i < 4; ++i) {
        const int row = row0 + i * 16;
#pragma unroll
        for (int r = 0; r < 4; ++r) {
          const float v = acc[i][j][r] + bvv;
          if (col < 256)
            KTp[(long long)((row + r) >> 5) * 8192 + (col >> 5) * 1024 +
                ((row + r) & 31) * 32 + (col & 31)] = f2h(v);
          else
            C2[(long long)(row + r) * 256 + (col - 256)] = f2h(v);
        }
      }
    }
    return;
  }

  float*  Cf = (float*)C;
  ushort* Ch = (ushort*)C;
#pragma unroll
  for (int j = 0; j < 4; ++j) {
    const int col = col0 + j * 16;
    const float bvv = bias ? bias[col] : 0.0f;
#pragma unroll
    for (int i = 0; i < 4; ++i) {
      const long long row = row0 + i * 16;
#pragma unroll
      for (int r = 0; r < 4; ++r) {
        float v = acc[i][j][r] + bvv;
        if (flags & 1) v = fmaxf(v, 0.0f);
        if (flags & 2) Ch[(row + r) * ldc + col] = f2h(v);
        else           Cf[(row + r) * ldc + col] = v;
      }
    }
  }
}

__global__ __launch_bounds__(256)
void gemm_bt(const ushort* __restrict__ A, int lda, long long sA,
             const ushort* __restrict__ B, int ldb, long long sB,
             const float* __restrict__ bias,
             void* __restrict__ C, int ldc, long long sC,
             int K, int flags)
{
  __shared__ ushort As[128 * 32];
  __shared__ ushort Bs[128 * 32];
  const int z = blockIdx.z;
  void* Cz = (flags & 2) ? (void*)((ushort*)C + (long long)z * sC)
                         : (void*)((float*)C + (long long)z * sC);
  gemm_body(A + (long long)z * sA, lda, B + (long long)z * sB, ldb, bias,
            Cz, ldc, K, flags, blockIdx.x, blockIdx.y, As, Bs);
}

// z=0: VT panels = (H[:,:1024] @ We2 + be2)  ; z=1: KT panels + Qm
__global__ __launch_bounds__(256)
void gemm2_pair(const ushort* __restrict__ H, const ushort* __restrict__ W2c,
                const float* __restrict__ be2, const float* __restrict__ bk2,
                ushort* __restrict__ VT, ushort* __restrict__ KT,
                ushort* __restrict__ Qm)
{
  __shared__ ushort As[128 * 32];
  __shared__ ushort Bs[128 * 32];
  if (blockIdx.z == 0)
    gemm_body(H, 2048, W2c, 1024, be2, VT, 0, 1024, 16,
              blockIdx.x, blockIdx.y, As, Bs);
  else
    gemm_body(H + 1024, 2048, W2c + 524288, 1024, bk2, KT, 0, 1024, 32,
              blockIdx.x, blockIdx.y, As, Bs, Qm);
}

// Flash attention, pipelined 1-barrier K-loop with double-buffered K/V LDS.
// Block = (batch, 64-q tile), 256 thr / 4 waves = (qg 2) x (dh 2).
// Wave: 32 q rows x 256 d cols, QK duplicated x2 across dh (Q in registers).
// K/V staged from pre-tiled panel layouts (KT/VT) -> fully sequential DMA.
// Softmax fully wave-local; P wave-private LDS (pad-40 stride).
// LDS: Ks 2x16KB + Vs 2x32KB + P 4x2.5KB = 106 KB -> 1 block/CU (grid=256).
__global__ __launch_bounds__(256, 1)
void attn_fused(const ushort* __restrict__ KT, const ushort* __restrict__ VT,
                const ushort* __restrict__ Qm, float* __restrict__ out)
{
  __shared__ ushort Ks[2][8192];    // [dc 8][tok 32][32]
  __shared__ ushort Vs[2][16384];   // [d 512][tok 32]
  __shared__ ushort Ps[4][1280];    // per-wave [q 32][40]

  const int tid  = threadIdx.x;
  const int lane = tid & 63;
  const int w    = tid >> 6;
  const int c    = lane & 15;
  const int quad = lane >> 4;
  const int qg   = w & 1;
  const int dh   = (w >> 1) << 8;         // 0 or 256
  const int z    = blockIdx.x;            // batch -> XCD locality
  const long long tb = (long long)z * 2048;
  const int q0   = blockIdx.y * 64;

  ushort* Pw = Ps[w];

  // Q a-frags in registers: 32 q x 256 d
  half8 qa[2][8];
#pragma unroll
  for (int i = 0; i < 2; ++i)
#pragma unroll
    for (int dc = 0; dc < 8; ++dc)
      qa[i][dc] = *(const half8*)(Qm + (tb + q0 + qg * 32 + i * 16 + c) * 256 +
                                  dc * 32 + quad * 8);

  float m_[2][4], l_[2][4];
#pragma unroll
  for (int i = 0; i < 2; ++i)
#pragma unroll
    for (int r = 0; r < 4; ++r) { m_[i][r] = -3.0e38f; l_[i][r] = 0.0f; }
  fx4 o[2][16] = {};

  // prologue: stage tile 0 into buffer 0
  {
    const long long pk = tb >> 5;
    const ushort* ksrc = KT + pk * 8192;
    const ushort* vsrc = VT + pk * 16384;
#pragma unroll
    for (int i = 0; i < 4; ++i) { const int u = i * 256 + tid; gload_lds16(ksrc + u * 8, &Ks[0][u * 8]); }
#pragma unroll
    for (int i = 0; i < 8; ++i) { const int u = i * 256 + tid; gload_lds16(vsrc + u * 8, &Vs[0][u * 8]); }
  }

  for (int it = 0; it < 64; ++it) {
    const int cb = it & 1;
    __syncthreads();                       // buf cb ready; old readers of cb^1 done
    if (it < 63) {                         // stage next tile into cb^1
      const long long pk = (tb >> 5) + it + 1;
      const ushort* ksrc = KT + pk * 8192;
      const ushort* vsrc = VT + pk * 16384;
#pragma unroll
      for (int i = 0; i < 4; ++i) { const int u = i * 256 + tid; gload_lds16(ksrc + u * 8, &Ks[cb ^ 1][u * 8]); }
#pragma unroll
      for (int i = 0; i < 8; ++i) { const int u = i * 256 + tid; gload_lds16(vsrc + u * 8, &Vs[cb ^ 1][u * 8]); }
    }

    // ---- QK: S[2 i][2 j] (32q x 32tok), K b-frags from LDS ----
    fx4 s[2][2] = {};
#pragma unroll
    for (int dc = 0; dc < 8; ++dc) {
      const half8 b0 = *(const half8*)(&Ks[cb][dc * 1024 + c * 32 + quad * 8]);
      const half8 b1 = *(const half8*)(&Ks[cb][dc * 1024 + (16 + c) * 32 + quad * 8]);
      s[0][0] = MFMA16(qa[0][dc], b0, s[0][0]); s[0][1] = MFMA16(qa[0][dc], b1, s[0][1]);
      s[1][0] = MFMA16(qa[1][dc], b0, s[1][0]); s[1][1] = MFMA16(qa[1][dc], b1, s[1][1]);
    }

    // ---- wave-local online softmax ----
    float alpha[2][4];
#pragma unroll
    for (int i = 0; i < 2; ++i) {
      fx4 rm;
#pragma unroll
      for (int r = 0; r < 4; ++r) rm[r] = fmaxf(s[i][0][r], s[i][1][r]);
#pragma unroll
      for (int off = 1; off < 16; off <<= 1)
#pragma unroll
        for (int r = 0; r < 4; ++r) rm[r] = fmaxf(rm[r], __shfl_xor(rm[r], off, 64));
#pragma unroll
      for (int r = 0; r < 4; ++r) {
        const float mn = fmaxf(m_[i][r], rm[r]);
        alpha[i][r] = __expf(m_[i][r] - mn);
        m_[i][r] = mn;
        const float e0 = __expf(s[i][0][r] - mn);
        const float e1 = __expf(s[i][1][r] - mn);
        l_[i][r] = alpha[i][r] * l_[i][r] + e0 + e1;   // per-lane partial (c-slice)
        Pw[(i * 16 + quad * 4 + r) * 40 + c]      = f2h(e0);
        Pw[(i * 16 + quad * 4 + r) * 40 + 16 + c] = f2h(e1);
      }
#pragma unroll
      for (int n = 0; n < 16; ++n)
#pragma unroll
        for (int r = 0; r < 4; ++r) o[i][n][r] *= alpha[i][r];
    }

    // ---- PV: pa from wave-private Ps, vb from LDS Vs ----
    half8 pa[2];
#pragma unroll
    for (int i = 0; i < 2; ++i)
      pa[i] = *(const half8*)(Pw + (i * 16 + c) * 40 + quad * 8);
#pragma unroll
    for (int n = 0; n < 16; ++n) {
      const half8 vb = *(const half8*)(&Vs[cb][(dh + n * 16 + c) * 32 + quad * 8]);
      o[0][n] = MFMA16(pa[0], vb, o[0][n]);
      o[1][n] = MFMA16(pa[1], vb, o[1][n]);
    }
  }

  // ---- epilogue: reduce l over 16-lane token groups, normalize, store ----
  float linv[2][4];
#pragma unroll
  for (int i = 0; i < 2; ++i) {
    fx4 lv;
#pragma unroll
    for (int r = 0; r < 4; ++r) lv[r] = l_[i][r];
#pragma unroll
    for (int off = 1; off < 16; off <<= 1)
#pragma unroll
      for (int r = 0; r < 4; ++r) lv[r] += __shfl_xor(lv[r], off, 64);
#pragma unroll
    for (int r = 0; r < 4; ++r) linv[i][r] = 1.0f / lv[r];
  }

  float* ob = out + (tb + q0 + qg * 32) * 512 + dh;
#pragma unroll
  for (int i = 0; i < 2; ++i)
#pragma unroll
    for (int n = 0; n < 16; ++n)
#pragma unroll
      for (int r = 0; r < 4; ++r)
        ob[(long long)(i * 16 + quad * 4 + r) * 512 + n * 16 + c] = o[i][n][r] * linv[i][r];
}

// fp32 [R][C] -> fp16 [C][R], two inputs selected by blockIdx.z
__global__ __launch_bounds__(256)
void transpose_cast_w2(const float* __restrict__ in0, const float* __restrict__ in1,
                       ushort* __restrict__ out0, ushort* __restrict__ out1,
                       int R, int C) {
  __shared__ float tile[32][33];
  const float* in  = blockIdx.z ? in1 : in0;
  ushort*      outp = blockIdx.z ? out1 : out0;
  const int c0 = blockIdx.x * 32, r0 = blockIdx.y * 32;
  const int tx = threadIdx.x & 31, ty = threadIdx.x >> 5;
#pragma unroll
  for (int i = 0; i < 32; i += 8)
    tile[ty + i][tx] = in[(long long)(r0 + ty + i) * C + (c0 + tx)];
  __syncthreads();
#pragma unroll
  for (int i = 0; i < 32; i += 8)
    outp[(long long)(c0 + ty + i) * R + (r0 + tx)] = f2h(tile[tx][ty + i]);
}

__global__ __launch_bounds__(256)
void cast_f32_f16(const float* __restrict__ in, ushort* __restrict__ out) {
  const long long i = ((long long)blockIdx.x * 256 + threadIdx.x) * 4;
  const float4 v = *(const float4*)(in + i);
  ushort4 o;
  o.x = f2h(v.x); o.y = f2h(v.y); o.z = f2h(v.z); o.w = f2h(v.w);
  *(ushort4*)(out + i) = o;
}

__global__ __launch_bounds__(256)
void concat_bias(const float* __restrict__ b0, const float* __restrict__ b1,
                 float* __restrict__ out) {
  const int i = blockIdx.x * 256 + threadIdx.x;
  out[i] = (i < 1024) ? b0[i] : b1[i - 1024];
}

extern "C" void kernel_launch(void* const* d_in, const int* in_sizes, int n_in,
                              void* d_out, int out_size, void* d_ws, size_t ws_size,
                              hipStream_t stream) {
  (void)in_sizes; (void)n_in; (void)out_size; (void)ws_size;
  const float* x   = (const float*)d_in[0];
  const float* We1 = (const float*)d_in[1];
  const float* be1 = (const float*)d_in[2];
  const float* We2 = (const float*)d_in[3];
  const float* be2 = (const float*)d_in[4];
  const float* Wk1 = (const float*)d_in[5];
  const float* bk1 = (const float*)d_in[6];
  const float* Wk2 = (const float*)d_in[7];
  const float* bk2 = (const float*)d_in[8];
  float* out = (float*)d_out;
  char* ws = (char*)d_ws;

  ushort* Xb  = (ushort*)(ws + 0);            // 16.78 MB, dead after gemm1
  ushort* W2c = (ushort*)(ws + 0);            // 2 MB, written after gemm1
  ushort* H   = (ushort*)(ws + 16777216);     // 16384x2048 fp16 = 67.1 MB
  ushort* VT  = (ushort*)(ws + 83886080);     // 512 panels x [512][32] = 16.78 MB
  ushort* KT  = (ushort*)(ws + 100663296);    // 512 panels x [8][32][32] = 8.39 MB
  ushort* Qm  = (ushort*)(ws + 109051904);    // 16384x256 fp16 = 8.39 MB
  float*  b1c = (float*)(ws + 117440512);     // 2048 fp32
  ushort* W1c = (ushort*)(ws + 117448704);    // 2 MB

  cast_f32_f16<<<dim3(8192), 256, 0, stream>>>(x, Xb);
  transpose_cast_w2<<<dim3(32, 16, 2), 256, 0, stream>>>(We1, Wk1, W1c, W1c + 524288, 512, 1024);
  concat_bias<<<dim3(8), 256, 0, stream>>>(be1, bk1, b1c);

  // H = relu(x @ [We1|Wk1] + [be1|bk1])   [16384,2048]
  gemm_bt<<<dim3(16, 128, 1), 256, 0, stream>>>(Xb, 512, 0, W1c, 512, 0, b1c,
                                                H, 2048, 0, 512, 1 | 2);

  transpose_cast_w2<<<dim3(16, 32, 2), 256, 0, stream>>>(We2, Wk2, W2c, W2c + 524288, 1024, 512);

  // z=0: VT panels ; z=1: KT panels + Qm
  gemm2_pair<<<dim3(4, 128, 2), 256, 0, stream>>>(H, W2c, be2, bk2, VT, KT, Qm);

  // flash attention: grid x=batch (XCD-local), y=64-q tile -> 256 blocks
  attn_fused<<<dim3(8, 32), 256, 0, stream>>>(KT, VT, Qm, out);
}